// Round 10
// baseline (257.392 us; speedup 1.0000x reference)
//
#include <hip/hip_runtime.h>
#include <math.h>

#define BB 4
#define TT 2048
#define DM 768
#define HD 64
#define NROW (BB*TT)   // 8192
#define WFRAG_HALF ((size_t)24*12*512)   // 147456 elems per part (hi | lo)

typedef __attribute__((ext_vector_type(8))) short bf16x8;
typedef __attribute__((ext_vector_type(4))) float f32x4;

__device__ __forceinline__ unsigned short f2bf(float f) {
    unsigned int u = __float_as_uint(f);
    u += 0x7FFFu + ((u >> 16) & 1u);   // RNE
    return (unsigned short)(u >> 16);
}
__device__ __forceinline__ float bf2f(unsigned short h) {
    return __uint_as_float(((unsigned int)h) << 16);
}

// -------- W -> MFMA-fragment-ordered bf16 hi/lo (round-5 verbatim) --------
__global__ __launch_bounds__(256) void wconv_kernel(
    const float* __restrict__ Wq, const float* __restrict__ Wk,
    const float* __restrict__ Wv, unsigned short* __restrict__ wfrag)
{
    __shared__ float ws[32][69];
    const int blk = blockIdx.x;
    const int m = blk / 24, kc = blk % 24;
    const float* Wm = (m == 0) ? Wq : ((m == 1) ? Wk : Wv);
    const float sc = (m == 0) ? 0.125f : 1.0f;
    const int tid = threadIdx.x;
    {
        int r = tid >> 3, c0 = (tid & 7) * 8;
        *(float4*)&ws[r][c0]     = *(const float4*)(Wm + (size_t)(32*kc + r)*HD + c0);
        *(float4*)&ws[r][c0 + 4] = *(const float4*)(Wm + (size_t)(32*kc + r)*HD + c0 + 4);
    }
    __syncthreads();
    const int ntm = tid >> 6, lane = tid & 63;
    const int q15 = lane & 15, g = lane >> 4;
    const int col = 16*ntm + q15;
    bf16x8 hi, lo;
    #pragma unroll
    for (int j = 0; j < 8; ++j) {
        float w = ws[8*g + j][col] * sc;
        unsigned short h = f2bf(w);
        hi[j] = (short)h;
        lo[j] = (short)f2bf(w - bf2f(h));
    }
    size_t base = ((size_t)((m*4 + ntm)*24 + kc))*512 + (size_t)lane*8;
    *(bf16x8*)(wfrag + base) = hi;
    *(bf16x8*)(wfrag + WFRAG_HALF + base) = lo;
}

// -------- QKV projection (round-5 verbatim: BK=128, dbuf LDS, 8 waves) --------
__global__ __launch_bounds__(512) void proj_mfma_kernel(
    const float* __restrict__ x, const unsigned short* __restrict__ wfrag,
    const float* __restrict__ bq, const float* __restrict__ bk,
    const float* __restrict__ bv,
    unsigned short* __restrict__ qo, unsigned short* __restrict__ ko,
    unsigned short* __restrict__ vT)
{
    __shared__ unsigned short xsh[2][2][32][132];
    const int tid  = threadIdx.x;
    const int wv   = tid >> 6;
    const int lane = tid & 63;
    const int q15  = lane & 15;
    const int g    = lane >> 4;
    const int row0 = blockIdx.x * 32;
    const int mt   = wv & 1;
    const int nt0  = 3 * (wv >> 1);
    const int xrow = 16*mt + q15;

    const int srow = tid >> 4;
    const int sc0  = (tid & 15) * 8;
    const float* xrp = x + (size_t)(row0 + srow)*DM + sc0;

    f32x4 acc[3];
    #pragma unroll
    for (int i = 0; i < 3; ++i) acc[i] = (f32x4){0.f, 0.f, 0.f, 0.f};

    {
        float4 xa = *(const float4*)(xrp);
        float4 xb = *(const float4*)(xrp + 4);
        bf16x8 hi, lo;
        float f[8] = {xa.x, xa.y, xa.z, xa.w, xb.x, xb.y, xb.z, xb.w};
        #pragma unroll
        for (int e = 0; e < 8; ++e) {
            unsigned short h = f2bf(f[e]);
            hi[e] = (short)h;
            lo[e] = (short)f2bf(f[e] - bf2f(h));
        }
        *(bf16x8*)&xsh[0][0][srow][sc0] = hi;
        *(bf16x8*)&xsh[0][1][srow][sc0] = lo;
    }
    __syncthreads();

    for (int t = 0; t < 6; ++t) {
        const int buf = t & 1;
        float4 xa, xb;
        if (t < 5) {
            xa = *(const float4*)(xrp + (t+1)*128);
            xb = *(const float4*)(xrp + (t+1)*128 + 4);
        }
        #pragma unroll
        for (int sub = 0; sub < 4; ++sub) {
            const int kcg = t*4 + sub;
            bf16x8 xfh = *(const bf16x8*)&xsh[buf][0][xrow][32*sub + 8*g];
            bf16x8 xfl = *(const bf16x8*)&xsh[buf][1][xrow][32*sub + 8*g];
            #pragma unroll
            for (int i = 0; i < 3; ++i) {
                const unsigned short* wp = wfrag + ((size_t)((nt0 + i)*24 + kcg))*512 + (size_t)lane*8;
                bf16x8 wh = *(const bf16x8*)wp;
                bf16x8 wl = *(const bf16x8*)(wp + WFRAG_HALF);
                acc[i] = __builtin_amdgcn_mfma_f32_16x16x32_bf16(xfh, wh, acc[i], 0, 0, 0);
                acc[i] = __builtin_amdgcn_mfma_f32_16x16x32_bf16(xfl, wh, acc[i], 0, 0, 0);
                acc[i] = __builtin_amdgcn_mfma_f32_16x16x32_bf16(xfh, wl, acc[i], 0, 0, 0);
            }
        }
        if (t < 5) {
            bf16x8 hi, lo;
            float f[8] = {xa.x, xa.y, xa.z, xa.w, xb.x, xb.y, xb.z, xb.w};
            #pragma unroll
            for (int e = 0; e < 8; ++e) {
                unsigned short h = f2bf(f[e]);
                hi[e] = (short)h;
                lo[e] = (short)f2bf(f[e] - bf2f(h));
            }
            *(bf16x8*)&xsh[buf^1][0][srow][sc0] = hi;
            *(bf16x8*)&xsh[buf^1][1][srow][sc0] = lo;
            __syncthreads();
        }
    }

    const int b  = row0 >> 11;
    const int t0 = row0 & 2047;
    #pragma unroll
    for (int i = 0; i < 3; ++i) {
        int nt = nt0 + i, m = nt >> 2, ntm = nt & 3;
        int col = 16*ntm + q15;
        float bb = (m == 0) ? 0.125f*bq[col] : ((m == 1) ? bk[col] : bv[col]);
        if (m == 2) {
            ushort4 pk;
            pk.x = f2bf(acc[i][0] + bb);
            pk.y = f2bf(acc[i][1] + bb);
            pk.z = f2bf(acc[i][2] + bb);
            pk.w = f2bf(acc[i][3] + bb);
            *(ushort4*)(vT + ((size_t)b*HD + col)*TT + t0 + 16*mt + 4*g) = pk;
        } else {
            unsigned short* op = (m == 0) ? qo : ko;
            #pragma unroll
            for (int r = 0; r < 4; ++r)
                op[(size_t)(row0 + 16*mt + 4*g + r)*HD + col] = f2bf(acc[i][r] + bb);
        }
    }
}

// -------- Flash attention (unchanged) --------
__global__ __launch_bounds__(256) void attn_mfma_kernel(
    const unsigned short* __restrict__ qb_, const unsigned short* __restrict__ kb_,
    const unsigned short* __restrict__ vt_, float* __restrict__ out)
{
    __shared__ unsigned short plds[4][16][40];
    __shared__ float olds[4][16][66];
    __shared__ float mlds[4][16][2];

    const int tid  = threadIdx.x;
    const int wv   = tid >> 6;
    const int lane = tid & 63;
    const int q15  = lane & 15;
    const int g    = lane >> 4;

    const int bx = blockIdx.x;
    const int b  = bx & 3;
    const int qt = (TT/16 - 1) - (bx >> 2);
    const int qbase = qt * 16;
    const int nk = qbase + 16;

    const unsigned short* qp = qb_ + (size_t)b*TT*HD;
    const unsigned short* kp = kb_ + (size_t)b*TT*HD;
    const unsigned short* vp = vt_ + (size_t)b*HD*TT;

    bf16x8 qf[2];
    #pragma unroll
    for (int c = 0; c < 2; ++c)
        qf[c] = *(const bf16x8*)(qp + (size_t)(qbase + q15)*HD + 32*c + 8*g);

    f32x4 accv[4];
    #pragma unroll
    for (int h = 0; h < 4; ++h) accv[h] = (f32x4){0.f, 0.f, 0.f, 0.f};
    float m = -INFINITY, l = 0.f;

    const int ck = ((nk + 127) >> 7) << 5;
    const int kstart = wv * ck;
    const int kend = min(kstart + ck, nk);

    for (int k0 = kstart; k0 < kend; k0 += 32) {
        bf16x8 vf[4];
        #pragma unroll
        for (int h = 0; h < 4; ++h)
            vf[h] = *(const bf16x8*)(vp + (size_t)(16*h + q15)*TT + k0 + 8*g);
        bf16x8 kf[2][2];
        #pragma unroll
        for (int t = 0; t < 2; ++t)
            #pragma unroll
            for (int c = 0; c < 2; ++c)
                kf[t][c] = *(const bf16x8*)(kp + (size_t)(k0 + 16*t + q15)*HD + 32*c + 8*g);

        f32x4 st[2];
        #pragma unroll
        for (int t = 0; t < 2; ++t) {
            f32x4 z = {0.f, 0.f, 0.f, 0.f};
            st[t] = __builtin_amdgcn_mfma_f32_16x16x32_bf16(kf[t][0], qf[0], z, 0, 0, 0);
            st[t] = __builtin_amdgcn_mfma_f32_16x16x32_bf16(kf[t][1], qf[1], st[t], 0, 0, 0);
        }
        if (k0 + 31 > qbase) {
            int qabs = qbase + q15;
            #pragma unroll
            for (int t = 0; t < 2; ++t)
                #pragma unroll
                for (int r = 0; r < 4; ++r)
                    if (k0 + 16*t + 4*g + r > qabs) st[t][r] = -INFINITY;
        }
        float pmax = st[0][0];
        #pragma unroll
        for (int t = 0; t < 2; ++t)
            #pragma unroll
            for (int r = 0; r < 4; ++r) pmax = fmaxf(pmax, st[t][r]);
        pmax = fmaxf(pmax, __shfl_xor(pmax, 16));
        pmax = fmaxf(pmax, __shfl_xor(pmax, 32));
        float mnew = fmaxf(m, pmax);
        float mc = fmaxf(mnew, -1e30f);
        float alpha = __expf(m - mc);
        float p[2][4];
        float psum = 0.f;
        #pragma unroll
        for (int t = 0; t < 2; ++t)
            #pragma unroll
            for (int r = 0; r < 4; ++r) {
                p[t][r] = __expf(st[t][r] - mc);
                psum += p[t][r];
            }
        psum += __shfl_xor(psum, 16);
        psum += __shfl_xor(psum, 32);
        l = l * alpha + psum;
        m = mnew;
        float av[4];
        #pragma unroll
        for (int r = 0; r < 4; ++r) av[r] = __shfl(alpha, 4*g + r);
        #pragma unroll
        for (int h = 0; h < 4; ++h)
            #pragma unroll
            for (int r = 0; r < 4; ++r) accv[h][r] *= av[r];
        #pragma unroll
        for (int t = 0; t < 2; ++t) {
            ushort4 pk;
            pk.x = f2bf(p[t][0]); pk.y = f2bf(p[t][1]);
            pk.z = f2bf(p[t][2]); pk.w = f2bf(p[t][3]);
            *(ushort4*)&plds[wv][q15][16*t + 4*g] = pk;
        }
        bf16x8 pa = *(const bf16x8*)&plds[wv][q15][8*g];
        #pragma unroll
        for (int h = 0; h < 4; ++h)
            accv[h] = __builtin_amdgcn_mfma_f32_16x16x32_bf16(pa, vf[h], accv[h], 0, 0, 0);
    }

    #pragma unroll
    for (int h = 0; h < 4; ++h)
        #pragma unroll
        for (int r = 0; r < 4; ++r)
            olds[wv][4*g + r][16*h + q15] = accv[h][r];
    if (g == 0) { mlds[wv][q15][0] = m; mlds[wv][q15][1] = l; }
    __syncthreads();

    {
        int qq = tid >> 4;
        int c4 = (tid & 15) << 2;
        float mw[4], lw[4];
        #pragma unroll
        for (int w = 0; w < 4; ++w) { mw[w] = mlds[w][qq][0]; lw[w] = mlds[w][qq][1]; }
        float M = fmaxf(fmaxf(mw[0], mw[1]), fmaxf(mw[2], mw[3]));
        float Mc = fmaxf(M, -1e30f);
        float ww[4], ltot = 0.f;
        #pragma unroll
        for (int w = 0; w < 4; ++w) { ww[w] = __expf(mw[w] - Mc); ltot += ww[w]*lw[w]; }
        float invl = 1.f / ltot;
        float4 o;
        #pragma unroll
        for (int e = 0; e < 4; ++e) {
            float s = 0.f;
            #pragma unroll
            for (int w = 0; w < 4; ++w) s += ww[w] * olds[w][qq][c4 + e];
            ((float*)&o)[e] = s * invl;
        }
        *(float4*)(out + ((size_t)b*TT + qbase + qq)*HD + c4) = o;
    }
}

// ================= ATTRIBUTION PROBES (write to dead scratch) =================
// A: W loads + MFMA (no x). Mirrors proj's W stream (8 waves, 6x16B/wave/iter).
__global__ __launch_bounds__(512) void probe_w_mfma(
    const unsigned short* __restrict__ wfrag, float* __restrict__ sink)
{
    const int tid = threadIdx.x;
    const int wv = tid >> 6, lane = tid & 63;
    const int nt0 = 3 * (wv >> 1);
    bf16x8 xf;
    #pragma unroll
    for (int e = 0; e < 8; ++e) xf[e] = (short)(0x3f80 ^ (lane + e));
    f32x4 acc[3];
    #pragma unroll
    for (int i = 0; i < 3; ++i) acc[i] = (f32x4){0.f,0.f,0.f,0.f};
    for (int p = 0; p < 4; ++p) {
        for (int kcg = 0; kcg < 24; ++kcg) {
            #pragma unroll
            for (int i = 0; i < 3; ++i) {
                const unsigned short* wp = wfrag + ((size_t)((nt0 + i)*24 + kcg))*512 + (size_t)lane*8;
                bf16x8 wh = *(const bf16x8*)wp;
                bf16x8 wl = *(const bf16x8*)(wp + WFRAG_HALF);
                acc[i] = __builtin_amdgcn_mfma_f32_16x16x32_bf16(xf, wh, acc[i], 0, 0, 0);
                acc[i] = __builtin_amdgcn_mfma_f32_16x16x32_bf16(xf, wl, acc[i], 0, 0, 0);
            }
        }
        asm volatile("" ::: "memory");
    }
    sink[(size_t)blockIdx.x*512 + tid] = acc[0][0] + acc[1][1] + acc[2][2];
}

// B: x loads + hi/lo cvt + MFMA (no W loads).
__global__ __launch_bounds__(512) void probe_x_mfma(
    const float* __restrict__ x, float* __restrict__ sink)
{
    const int tid = threadIdx.x;
    const int wv = tid >> 6, lane = tid & 63;
    const int q15 = lane & 15, g = lane >> 4;
    const int mt = wv & 1;
    const int row0 = blockIdx.x * 32;
    const float* xp = x + (size_t)(row0 + 16*mt + q15)*DM + 8*g;
    bf16x8 wf;
    #pragma unroll
    for (int e = 0; e < 8; ++e) wf[e] = (short)(0x3f00 ^ (lane*3 + e));
    f32x4 acc[3];
    #pragma unroll
    for (int i = 0; i < 3; ++i) acc[i] = (f32x4){0.f,0.f,0.f,0.f};
    for (int p = 0; p < 4; ++p) {
        for (int kcg = 0; kcg < 24; ++kcg) {
            float4 xa = *(const float4*)(xp + 32*kcg);
            float4 xb = *(const float4*)(xp + 32*kcg + 4);
            bf16x8 xfh, xfl;
            float f[8] = {xa.x, xa.y, xa.z, xa.w, xb.x, xb.y, xb.z, xb.w};
            #pragma unroll
            for (int e = 0; e < 8; ++e) {
                unsigned short h = (unsigned short)(__float_as_uint(f[e]) >> 16);
                float r = f[e] - bf2f(h);
                xfh[e] = (short)h;
                xfl[e] = (short)(unsigned short)(__float_as_uint(r) >> 16);
            }
            acc[0] = __builtin_amdgcn_mfma_f32_16x16x32_bf16(xfh, wf, acc[0], 0, 0, 0);
            acc[1] = __builtin_amdgcn_mfma_f32_16x16x32_bf16(xfl, wf, acc[1], 0, 0, 0);
            acc[2] = __builtin_amdgcn_mfma_f32_16x16x32_bf16(xfh, wf, acc[2], 0, 0, 0);
        }
        asm volatile("" ::: "memory");
    }
    sink[(size_t)blockIdx.x*512 + tid] = acc[0][0] + acc[1][1] + acc[2][2];
}

// C: MFMA-only chain (PL=32). Visible in top-5 only if compute/clock is broken.
__global__ __launch_bounds__(512) void probe_compute(float* __restrict__ sink)
{
    const int tid = threadIdx.x, lane = tid & 63;
    bf16x8 a, b;
    #pragma unroll
    for (int e = 0; e < 8; ++e) { a[e] = (short)(0x3f80 ^ (lane+e)); b[e] = (short)(0x3f00 ^ (lane*5+e)); }
    f32x4 acc[3];
    #pragma unroll
    for (int i = 0; i < 3; ++i) acc[i] = (f32x4){0.f,0.f,0.f,0.f};
    for (int p = 0; p < 32; ++p) {
        for (int kcg = 0; kcg < 24; ++kcg) {
            #pragma unroll
            for (int i = 0; i < 3; ++i) {
                acc[i] = __builtin_amdgcn_mfma_f32_16x16x32_bf16(a, b, acc[i], 0, 0, 0);
                acc[i] = __builtin_amdgcn_mfma_f32_16x16x32_bf16(b, a, acc[i], 0, 0, 0);
                acc[i] = __builtin_amdgcn_mfma_f32_16x16x32_bf16(a, a, acc[i], 0, 0, 0);
            }
        }
        asm volatile("" ::: "memory");
    }
    sink[(size_t)blockIdx.x*512 + tid] = acc[0][0] + acc[1][1] + acc[2][2];
}

// D: W loads only (no MFMA) — raw L2/L3 BW + latency.
__global__ __launch_bounds__(512) void probe_w_loads(
    const unsigned short* __restrict__ wfrag, float* __restrict__ sink)
{
    const int tid = threadIdx.x;
    const int wv = tid >> 6, lane = tid & 63;
    const int nt0 = 3 * (wv >> 1);
    uint4 acc = {0u,0u,0u,0u};
    for (int p = 0; p < 4; ++p) {
        for (int kcg = 0; kcg < 24; ++kcg) {
            #pragma unroll
            for (int i = 0; i < 3; ++i) {
                const unsigned short* wp = wfrag + ((size_t)((nt0 + i)*24 + kcg))*512 + (size_t)lane*8;
                uint4 a = *(const uint4*)wp;
                uint4 b = *(const uint4*)(wp + WFRAG_HALF);
                acc.x ^= a.x ^ b.x; acc.y ^= a.y ^ b.y;
                acc.z ^= a.z ^ b.z; acc.w ^= a.w ^ b.w;
            }
        }
        asm volatile("" ::: "memory");
    }
    sink[(size_t)blockIdx.x*512 + tid] = (float)(acc.x ^ acc.y ^ acc.z ^ acc.w);
}

extern "C" void kernel_launch(void* const* d_in, const int* in_sizes, int n_in,
                              void* d_out, int out_size, void* d_ws, size_t ws_size,
                              hipStream_t stream) {
    const float* x  = (const float*)d_in[0];
    const float* Wq = (const float*)d_in[1];
    const float* bq = (const float*)d_in[2];
    const float* Wk = (const float*)d_in[3];
    const float* bk = (const float*)d_in[4];
    const float* Wv = (const float*)d_in[5];
    const float* bv = (const float*)d_in[6];
    float* out = (float*)d_out;

    unsigned short* qbf   = (unsigned short*)d_ws;
    unsigned short* kbf   = qbf + (size_t)NROW*HD;
    unsigned short* vT    = kbf + (size_t)NROW*HD;
    unsigned short* wfrag = vT  + (size_t)NROW*HD;   // 576 KB
    float* sinkA = (float*)(wfrag + 2*WFRAG_HALF);
    float* sinkB = sinkA + 256*512;
    float* sinkC = sinkB + 256*512;
    float* sinkD = sinkC + 256*512;

    wconv_kernel<<<72, 256, 0, stream>>>(Wq, Wk, Wv, wfrag);
    proj_mfma_kernel<<<NROW/32, 512, 0, stream>>>(x, wfrag, bq, bk, bv, qbf, kbf, vT);
    attn_mfma_kernel<<<dim3(TT/16 * BB), 256, 0, stream>>>(qbf, kbf, vT, out);

    // attribution probes (dead scratch; deterministic)
    probe_w_mfma<<<256, 512, 0, stream>>>(wfrag, sinkA);
    probe_x_mfma<<<256, 512, 0, stream>>>(x, sinkB);
    probe_compute<<<256, 512, 0, stream>>>(sinkC);
    probe_w_loads<<<256, 512, 0, stream>>>(wfrag, sinkD);
}

// Round 11
// 59.816 us; speedup vs baseline: 4.3031x; 4.3031x over previous
//
#include <hip/hip_runtime.h>
#include <math.h>

#define BB 4
#define TT 2048
#define DM 768
#define HD 64
#define NROW (BB*TT)   // 8192
#define WFRAG_HALF ((size_t)24*12*512)   // 147456 elems per part (hi | lo)

typedef __attribute__((ext_vector_type(8))) short bf16x8;
typedef __attribute__((ext_vector_type(4))) float f32x4;

__device__ __forceinline__ unsigned short f2bf(float f) {
    unsigned int u = __float_as_uint(f);
    u += 0x7FFFu + ((u >> 16) & 1u);   // RNE
    return (unsigned short)(u >> 16);
}
__device__ __forceinline__ float bf2f(unsigned short h) {
    return __uint_as_float(((unsigned int)h) << 16);
}

// async 16B/lane global->LDS: LDS dest wave-uniform base + lane*16
__device__ __forceinline__ void g2lds16(const unsigned short* g, unsigned short* l) {
    __builtin_amdgcn_global_load_lds(
        (const __attribute__((address_space(1))) unsigned int*)g,
        (__attribute__((address_space(3))) unsigned int*)l, 16, 0, 0);
}

// -------- W -> fragment-ordered bf16 hi/lo, layout [nt(12)][kc(24)][512] --------
__global__ __launch_bounds__(256) void wconv_kernel(
    const float* __restrict__ Wq, const float* __restrict__ Wk,
    const float* __restrict__ Wv, unsigned short* __restrict__ wfrag)
{
    __shared__ float ws[32][69];
    const int blk = blockIdx.x;          // 0..71 = m*24 + kc
    const int m = blk / 24, kc = blk % 24;
    const float* Wm = (m == 0) ? Wq : ((m == 1) ? Wk : Wv);
    const float sc = (m == 0) ? 0.125f : 1.0f;
    const int tid = threadIdx.x;
    {
        int r = tid >> 3, c0 = (tid & 7) * 8;
        *(float4*)&ws[r][c0]     = *(const float4*)(Wm + (size_t)(32*kc + r)*HD + c0);
        *(float4*)&ws[r][c0 + 4] = *(const float4*)(Wm + (size_t)(32*kc + r)*HD + c0 + 4);
    }
    __syncthreads();
    const int ntm = tid >> 6, lane = tid & 63;
    const int q15 = lane & 15, g = lane >> 4;
    const int col = 16*ntm + q15;
    bf16x8 hi, lo;
    #pragma unroll
    for (int j = 0; j < 8; ++j) {
        float w = ws[8*g + j][col] * sc;
        unsigned short h = f2bf(w);
        hi[j] = (short)h;
        lo[j] = (short)f2bf(w - bf2f(h));
    }
    size_t base = ((size_t)((m*4 + ntm)*24 + kc))*512 + (size_t)lane*8;
    *(bf16x8*)(wfrag + base) = hi;
    *(bf16x8*)(wfrag + WFRAG_HALF + base) = lo;
}

// -------- QKV projection: per-block W fully LDS-resident, barrier-free K-loop --------
// grid 256 = 64 row-groups(128 rows) x 4 nt-trios. 256 thr = 4 waves; wave w owns
// rows [rt0+32w, rt0+32w+32), computing nt = 3*ng..3*ng+2 for both 16-row halves.
// Dynamic LDS: wlds[kcg(24)][part(2)][ntl(3)][512] = 144 KB.
__global__ __launch_bounds__(256, 1) void proj_mfma_kernel(
    const float* __restrict__ x, const unsigned short* __restrict__ wfrag,
    const float* __restrict__ bq, const float* __restrict__ bk,
    const float* __restrict__ bv,
    unsigned short* __restrict__ qo, unsigned short* __restrict__ ko,
    unsigned short* __restrict__ vT)
{
    extern __shared__ unsigned short wlds[];
    const int tid  = threadIdx.x;
    const int wv   = tid >> 6;
    const int lane = tid & 63;
    const int q15  = lane & 15;
    const int g    = lane >> 4;
    const int bx   = blockIdx.x;
    const int ng   = bx & 3;
    const int rt0  = (bx >> 2) * 128;
    const int wrow0 = rt0 + 32*wv;

    // ---- stage ALL W for this nt-trio: 144 x 1KB fragments, 36 per wave ----
    #pragma unroll
    for (int j = 0; j < 36; ++j) {
        const int s = wv*36 + j;             // 0..143 = kcg*6 + part*3 + ntl
        const int kcg = s / 6, r6 = s % 6;
        const int part = r6 / 3, ntl = r6 % 3;
        const unsigned short* src = wfrag + (size_t)part*WFRAG_HALF
            + ((size_t)((3*ng + ntl)*24 + kcg))*512 + (size_t)lane*8;
        g2lds16(src, wlds + (size_t)s*512);
    }

    // ---- x prefetch ring (4 deep, static-indexed), issued before the barrier ----
    const float* xp0 = x + (size_t)(wrow0 + q15)*DM + 8*g;        // mt=0 rows
    const float* xp1 = x + (size_t)(wrow0 + 16 + q15)*DM + 8*g;   // mt=1 rows
    float4 pf[4][2][2];
    #pragma unroll
    for (int kb = 0; kb < 4; ++kb) {
        pf[kb][0][0] = *(const float4*)(xp0 + 32*kb);
        pf[kb][0][1] = *(const float4*)(xp0 + 32*kb + 4);
        pf[kb][1][0] = *(const float4*)(xp1 + 32*kb);
        pf[kb][1][1] = *(const float4*)(xp1 + 32*kb + 4);
    }
    __syncthreads();   // W staged (vmcnt drained once); wlds read-only hereafter

    f32x4 acc[2][3];
    #pragma unroll
    for (int mt = 0; mt < 2; ++mt)
        #pragma unroll
        for (int i = 0; i < 3; ++i) acc[mt][i] = (f32x4){0.f, 0.f, 0.f, 0.f};

    #pragma unroll
    for (int kb = 0; kb < 24; ++kb) {
        const int slot = kb & 3;
        // convert this chunk's x (truncation hi/lo split)
        bf16x8 xh[2], xl[2];
        #pragma unroll
        for (int mt = 0; mt < 2; ++mt) {
            float f[8] = {pf[slot][mt][0].x, pf[slot][mt][0].y,
                          pf[slot][mt][0].z, pf[slot][mt][0].w,
                          pf[slot][mt][1].x, pf[slot][mt][1].y,
                          pf[slot][mt][1].z, pf[slot][mt][1].w};
            #pragma unroll
            for (int e = 0; e < 8; ++e) {
                unsigned short h = (unsigned short)(__float_as_uint(f[e]) >> 16);
                float rr = f[e] - bf2f(h);
                xh[mt][e] = (short)h;
                xl[mt][e] = (short)(unsigned short)(__float_as_uint(rr) >> 16);
            }
        }
        // refill this slot for kb+4
        if (kb < 20) {
            pf[slot][0][0] = *(const float4*)(xp0 + 32*(kb+4));
            pf[slot][0][1] = *(const float4*)(xp0 + 32*(kb+4) + 4);
            pf[slot][1][0] = *(const float4*)(xp1 + 32*(kb+4));
            pf[slot][1][1] = *(const float4*)(xp1 + 32*(kb+4) + 4);
        }
        // W from LDS + 18 MFMA (6 independent acc chains)
        #pragma unroll
        for (int i = 0; i < 3; ++i) {
            bf16x8 wh = *(const bf16x8*)(wlds + (size_t)(kb*6 + i)*512     + (size_t)lane*8);
            bf16x8 wl = *(const bf16x8*)(wlds + (size_t)(kb*6 + 3 + i)*512 + (size_t)lane*8);
            #pragma unroll
            for (int mt = 0; mt < 2; ++mt) {
                acc[mt][i] = __builtin_amdgcn_mfma_f32_16x16x32_bf16(xh[mt], wh, acc[mt][i], 0, 0, 0);
                acc[mt][i] = __builtin_amdgcn_mfma_f32_16x16x32_bf16(xl[mt], wh, acc[mt][i], 0, 0, 0);
                acc[mt][i] = __builtin_amdgcn_mfma_f32_16x16x32_bf16(xh[mt], wl, acc[mt][i], 0, 0, 0);
            }
        }
    }

    // ---- epilogue (round-5 semantics) ----
    const int b  = wrow0 >> 11;
    const int t0 = wrow0 & 2047;
    #pragma unroll
    for (int i = 0; i < 3; ++i) {
        const int nt = 3*ng + i, m = nt >> 2, ntm = nt & 3;
        const int col = 16*ntm + q15;
        const float bb = (m == 0) ? 0.125f*bq[col] : ((m == 1) ? bk[col] : bv[col]);
        #pragma unroll
        for (int mt = 0; mt < 2; ++mt) {
            if (m == 2) {
                ushort4 pk;
                pk.x = f2bf(acc[mt][i][0] + bb);
                pk.y = f2bf(acc[mt][i][1] + bb);
                pk.z = f2bf(acc[mt][i][2] + bb);
                pk.w = f2bf(acc[mt][i][3] + bb);
                *(ushort4*)(vT + ((size_t)b*HD + col)*TT + t0 + 16*mt + 4*g) = pk;
            } else {
                unsigned short* op = (m == 0) ? qo : ko;
                #pragma unroll
                for (int r = 0; r < 4; ++r)
                    op[(size_t)(wrow0 + 16*mt + 4*g + r)*HD + col] = f2bf(acc[mt][i][r] + bb);
            }
        }
    }
}

// -------- Flash attention: bf16 MFMA, in-block 4-way key split (unchanged) --------
__global__ __launch_bounds__(256) void attn_mfma_kernel(
    const unsigned short* __restrict__ qb_, const unsigned short* __restrict__ kb_,
    const unsigned short* __restrict__ vt_, float* __restrict__ out)
{
    __shared__ unsigned short plds[4][16][40];
    __shared__ float olds[4][16][66];
    __shared__ float mlds[4][16][2];

    const int tid  = threadIdx.x;
    const int wv   = tid >> 6;
    const int lane = tid & 63;
    const int q15  = lane & 15;
    const int g    = lane >> 4;

    const int bx = blockIdx.x;
    const int b  = bx & 3;
    const int qt = (TT/16 - 1) - (bx >> 2);
    const int qbase = qt * 16;
    const int nk = qbase + 16;

    const unsigned short* qp = qb_ + (size_t)b*TT*HD;
    const unsigned short* kp = kb_ + (size_t)b*TT*HD;
    const unsigned short* vp = vt_ + (size_t)b*HD*TT;

    bf16x8 qf[2];
    #pragma unroll
    for (int c = 0; c < 2; ++c)
        qf[c] = *(const bf16x8*)(qp + (size_t)(qbase + q15)*HD + 32*c + 8*g);

    f32x4 accv[4];
    #pragma unroll
    for (int h = 0; h < 4; ++h) accv[h] = (f32x4){0.f, 0.f, 0.f, 0.f};
    float m = -INFINITY, l = 0.f;

    const int ck = ((nk + 127) >> 7) << 5;
    const int kstart = wv * ck;
    const int kend = min(kstart + ck, nk);

    for (int k0 = kstart; k0 < kend; k0 += 32) {
        bf16x8 vf[4];
        #pragma unroll
        for (int h = 0; h < 4; ++h)
            vf[h] = *(const bf16x8*)(vp + (size_t)(16*h + q15)*TT + k0 + 8*g);
        bf16x8 kf[2][2];
        #pragma unroll
        for (int t = 0; t < 2; ++t)
            #pragma unroll
            for (int c = 0; c < 2; ++c)
                kf[t][c] = *(const bf16x8*)(kp + (size_t)(k0 + 16*t + q15)*HD + 32*c + 8*g);

        f32x4 st[2];
        #pragma unroll
        for (int t = 0; t < 2; ++t) {
            f32x4 z = {0.f, 0.f, 0.f, 0.f};
            st[t] = __builtin_amdgcn_mfma_f32_16x16x32_bf16(kf[t][0], qf[0], z, 0, 0, 0);
            st[t] = __builtin_amdgcn_mfma_f32_16x16x32_bf16(kf[t][1], qf[1], st[t], 0, 0, 0);
        }
        if (k0 + 31 > qbase) {
            int qabs = qbase + q15;
            #pragma unroll
            for (int t = 0; t < 2; ++t)
                #pragma unroll
                for (int r = 0; r < 4; ++r)
                    if (k0 + 16*t + 4*g + r > qabs) st[t][r] = -INFINITY;
        }
        float pmax = st[0][0];
        #pragma unroll
        for (int t = 0; t < 2; ++t)
            #pragma unroll
            for (int r = 0; r < 4; ++r) pmax = fmaxf(pmax, st[t][r]);
        pmax = fmaxf(pmax, __shfl_xor(pmax, 16));
        pmax = fmaxf(pmax, __shfl_xor(pmax, 32));
        float mnew = fmaxf(m, pmax);
        float mc = fmaxf(mnew, -1e30f);
        float alpha = __expf(m - mc);
        float p[2][4];
        float psum = 0.f;
        #pragma unroll
        for (int t = 0; t < 2; ++t)
            #pragma unroll
            for (int r = 0; r < 4; ++r) {
                p[t][r] = __expf(st[t][r] - mc);
                psum += p[t][r];
            }
        psum += __shfl_xor(psum, 16);
        psum += __shfl_xor(psum, 32);
        l = l * alpha + psum;
        m = mnew;
        float av[4];
        #pragma unroll
        for (int r = 0; r < 4; ++r) av[r] = __shfl(alpha, 4*g + r);
        #pragma unroll
        for (int h = 0; h < 4; ++h)
            #pragma unroll
            for (int r = 0; r < 4; ++r) accv[h][r] *= av[r];
        #pragma unroll
        for (int t = 0; t < 2; ++t) {
            ushort4 pk;
            pk.x = f2bf(p[t][0]); pk.y = f2bf(p[t][1]);
            pk.z = f2bf(p[t][2]); pk.w = f2bf(p[t][3]);
            *(ushort4*)&plds[wv][q15][16*t + 4*g] = pk;
        }
        bf16x8 pa = *(const bf16x8*)&plds[wv][q15][8*g];
        #pragma unroll
        for (int h = 0; h < 4; ++h)
            accv[h] = __builtin_amdgcn_mfma_f32_16x16x32_bf16(pa, vf[h], accv[h], 0, 0, 0);
    }

    #pragma unroll
    for (int h = 0; h < 4; ++h)
        #pragma unroll
        for (int r = 0; r < 4; ++r)
            olds[wv][4*g + r][16*h + q15] = accv[h][r];
    if (g == 0) { mlds[wv][q15][0] = m; mlds[wv][q15][1] = l; }
    __syncthreads();

    {
        int qq = tid >> 4;
        int c4 = (tid & 15) << 2;
        float mw[4], lw[4];
        #pragma unroll
        for (int w = 0; w < 4; ++w) { mw[w] = mlds[w][qq][0]; lw[w] = mlds[w][qq][1]; }
        float M = fmaxf(fmaxf(mw[0], mw[1]), fmaxf(mw[2], mw[3]));
        float Mc = fmaxf(M, -1e30f);
        float ww[4], ltot = 0.f;
        #pragma unroll
        for (int w = 0; w < 4; ++w) { ww[w] = __expf(mw[w] - Mc); ltot += ww[w]*lw[w]; }
        float invl = 1.f / ltot;
        float4 o;
        #pragma unroll
        for (int e = 0; e < 4; ++e) {
            float s = 0.f;
            #pragma unroll
            for (int w = 0; w < 4; ++w) s += ww[w] * olds[w][qq][c4 + e];
            ((float*)&o)[e] = s * invl;
        }
        *(float4*)(out + ((size_t)b*TT + qbase + qq)*HD + c4) = o;
    }
}

extern "C" void kernel_launch(void* const* d_in, const int* in_sizes, int n_in,
                              void* d_out, int out_size, void* d_ws, size_t ws_size,
                              hipStream_t stream) {
    const float* x  = (const float*)d_in[0];
    const float* Wq = (const float*)d_in[1];
    const float* bq = (const float*)d_in[2];
    const float* Wk = (const float*)d_in[3];
    const float* bk = (const float*)d_in[4];
    const float* Wv = (const float*)d_in[5];
    const float* bv = (const float*)d_in[6];
    float* out = (float*)d_out;

    unsigned short* qbf   = (unsigned short*)d_ws;
    unsigned short* kbf   = qbf + (size_t)NROW*HD;
    unsigned short* vT    = kbf + (size_t)NROW*HD;
    unsigned short* wfrag = vT  + (size_t)NROW*HD;   // 576 KB

    // allow 144 KB dynamic LDS for proj (idempotent host-side call)
    hipFuncSetAttribute((const void*)proj_mfma_kernel,
                        hipFuncAttributeMaxDynamicSharedMemorySize, 147456);

    wconv_kernel<<<72, 256, 0, stream>>>(Wq, Wk, Wv, wfrag);
    proj_mfma_kernel<<<256, 256, 147456, stream>>>(x, wfrag, bq, bk, bv, qbf, kbf, vT);
    attn_mfma_kernel<<<dim3(TT/16 * BB), 256, 0, stream>>>(qbf, kbf, vT, out);
}